// Round 7
// baseline (646.598 us; speedup 1.0000x reference)
//
#include <hip/hip_runtime.h>
#include <hip/hip_bf16.h>

#define N_NODES 100000
#define N_EDGES 1600000
#define IN_DIM 128
#define HID 256
#define NUM_GRAPHS 2048
#define M_PAD 100096  // 782 * 128
#define SCAN_BLOCKS 98  // ceil(100000/1024)

typedef __bf16 bf16x8 __attribute__((ext_vector_type(8)));
typedef float f32x4 __attribute__((ext_vector_type(4)));

__device__ inline unsigned short f2bf(float x) {
    union { __hip_bfloat16 h; unsigned short u; } v;
    v.h = __float2bfloat16(x);
    return v.u;
}
__device__ inline float bf2f(unsigned short u) {
    return __uint_as_float(((unsigned int)u) << 16);
}

// ---------------- degree histogram over dst ----------------
__global__ void count_deg_kernel(const int* __restrict__ ei, int* __restrict__ deg) {
    int e = blockIdx.x * blockDim.x + threadIdx.x;
    if (e < N_EDGES) {
        atomicAdd(&deg[ei[N_EDGES + e]], 1);
    }
}

// ---------------- block sums (+ fused dinv) ----------------
__global__ __launch_bounds__(1024) void blocksum_kernel(const int* __restrict__ deg,
                                                        int* __restrict__ bsum,
                                                        float* __restrict__ dinv) {
    int i = blockIdx.x * 1024 + threadIdx.x;
    int v = (i < N_NODES) ? deg[i] : 0;
    if (i < N_NODES) dinv[i] = rsqrtf((float)(v + 1));  // self-loop adds 1
    __shared__ int s[1024];
    int t = threadIdx.x;
    s[t] = v;
    __syncthreads();
#pragma unroll
    for (int off = 512; off > 0; off >>= 1) {
        if (t < off) s[t] += s[t + off];
        __syncthreads();
    }
    if (t == 0) bsum[blockIdx.x] = s[0];
}

__global__ __launch_bounds__(128) void bscan_kernel(int* __restrict__ bsum) {
    __shared__ int s[128];
    int t = threadIdx.x;
    int v = (t < SCAN_BLOCKS) ? bsum[t] : 0;
    s[t] = v;
    __syncthreads();
#pragma unroll
    for (int off = 1; off < 128; off <<= 1) {
        int x = (t >= off) ? s[t - off] : 0;
        __syncthreads();
        s[t] += x;
        __syncthreads();
    }
    if (t < SCAN_BLOCKS) bsum[t] = (t > 0) ? s[t - 1] : 0;  // exclusive
}

__global__ __launch_bounds__(1024) void scanout_kernel(const int* __restrict__ deg,
                                                       const int* __restrict__ bsum,
                                                       int* __restrict__ rowptr) {
    int i = blockIdx.x * 1024 + threadIdx.x;
    int t = threadIdx.x;
    int v = (i < N_NODES) ? deg[i] : 0;
    __shared__ int s[1024];
    s[t] = v;
    __syncthreads();
#pragma unroll
    for (int off = 1; off < 1024; off <<= 1) {
        int x = (t >= off) ? s[t - off] : 0;
        __syncthreads();
        s[t] += x;
        __syncthreads();
    }
    int base = bsum[blockIdx.x];
    int excl = (t > 0) ? s[t - 1] : 0;
    if (i < N_NODES) rowptr[i] = base + excl;
    if (i == N_NODES - 1) rowptr[N_NODES] = base + s[t];
}

// ---------------- bucket fill: CSR src list sorted by dst ----------------
__global__ void fill_kernel(const int* __restrict__ ei, const int* __restrict__ rowptr,
                            int* __restrict__ fill, int* __restrict__ esrc) {
    int e = blockIdx.x * blockDim.x + threadIdx.x;
    if (e < N_EDGES) {
        int dst = ei[N_EDGES + e];
        int pos = rowptr[dst] + atomicAdd(&fill[dst], 1);
        esrc[pos] = ei[e];
    }
}

// ---------------- x -> bf16 ----------------
__global__ void x2bf_kernel(const float* __restrict__ x, unsigned short* __restrict__ xb) {
    size_t i = ((size_t)blockIdx.x * 256 + threadIdx.x) * 4;
    float4 v = *(const float4*)(x + i);
    ushort4 o;
    o.x = f2bf(v.x); o.y = f2bf(v.y); o.z = f2bf(v.z); o.w = f2bf(v.w);
    *(ushort4*)(xb + i) = o;
}

// ---------------- both weight transposes + bf16 splits in one launch ----------
__global__ void wsplit_all_kernel(const float* __restrict__ W1, const float* __restrict__ W2,
                                  unsigned short* __restrict__ W1th, unsigned short* __restrict__ W1tl,
                                  unsigned short* __restrict__ W2th, unsigned short* __restrict__ W2tl) {
    int idx = blockIdx.x * 256 + threadIdx.x;
    if (idx < IN_DIM * 256) {
        int k = idx >> 8, n = idx & 255;
        float w = W1[idx];
        unsigned short h = f2bf(w);
        unsigned short l = f2bf(w - bf2f(h));
        W1th[n * IN_DIM + k] = h;
        W1tl[n * IN_DIM + k] = l;
    } else {
        int i2 = idx - IN_DIM * 256;
        int k = i2 >> 8, n = i2 & 255;
        float w = W2[i2];
        unsigned short h = f2bf(w);
        unsigned short l = f2bf(w - bf2f(h));
        W2th[n * HID + k] = h;
        W2tl[n * HID + k] = l;
    }
}

// ---------------- gather agg 128-dim from bf16, writes bf16 hi/lo split ----------
// predicated uniform 8-wide loop: no serial tail, OOB lanes clamp to e-1 (L2 hit) w/ w=0
__global__ __launch_bounds__(256) void agg128_kernel(const unsigned short* __restrict__ X,
                                                     const int* __restrict__ esrc,
                                                     const int* __restrict__ rowptr,
                                                     const float* __restrict__ dinv,
                                                     unsigned short* __restrict__ Ah,
                                                     unsigned short* __restrict__ Al) {
    int node = blockIdx.x * 4 + (threadIdx.x >> 6);
    int lane = threadIdx.x & 63;
    if (node >= N_NODES) return;
    float ddst = dinv[node];
    int s = rowptr[node], e = rowptr[node + 1];

    float w0 = ddst * ddst;
    ushort2 h0 = *(const ushort2*)(X + (size_t)node * 128 + lane * 2);
    float2 acc = make_float2(w0 * bf2f(h0.x), w0 * bf2f(h0.y));

    for (int j = s; j < e; j += 8) {
        int si[8];
#pragma unroll
        for (int u = 0; u < 8; u++) {
            int jj = j + u;
            si[u] = esrc[(jj < e) ? jj : (e - 1)];
        }
        ushort2 xv[8];
#pragma unroll
        for (int u = 0; u < 8; u++)
            xv[u] = *(const ushort2*)(X + (size_t)si[u] * 128 + lane * 2);
        float a[8];
#pragma unroll
        for (int u = 0; u < 8; u++)
            a[u] = (j + u < e) ? dinv[si[u]] * ddst : 0.f;
#pragma unroll
        for (int u = 0; u < 8; u++) {
            acc.x = fmaf(a[u], bf2f(xv[u].x), acc.x);
            acc.y = fmaf(a[u], bf2f(xv[u].y), acc.y);
        }
    }
    size_t o = (size_t)node * 128 + lane * 2;
    ushort2 hi, lo;
    hi.x = f2bf(acc.x); lo.x = f2bf(acc.x - bf2f(hi.x));
    hi.y = f2bf(acc.y); lo.y = f2bf(acc.y - bf2f(hi.y));
    *(ushort2*)(Ah + o) = hi;
    *(ushort2*)(Al + o) = lo;
}

// ---------------- gather agg 256-dim from bf16, writes bf16 (hi only) ----------
__global__ __launch_bounds__(256) void agg256_kernel(const unsigned short* __restrict__ H,
                                                     const int* __restrict__ esrc,
                                                     const int* __restrict__ rowptr,
                                                     const float* __restrict__ dinv,
                                                     unsigned short* __restrict__ Ah) {
    int node = blockIdx.x * 4 + (threadIdx.x >> 6);
    int lane = threadIdx.x & 63;
    if (node >= N_NODES) return;
    float ddst = dinv[node];
    int s = rowptr[node], e = rowptr[node + 1];

    float w0 = ddst * ddst;
    ushort4 h0 = *(const ushort4*)(H + (size_t)node * 256 + lane * 4);
    float4 acc = make_float4(w0 * bf2f(h0.x), w0 * bf2f(h0.y),
                             w0 * bf2f(h0.z), w0 * bf2f(h0.w));

    for (int j = s; j < e; j += 8) {
        int si[8];
#pragma unroll
        for (int u = 0; u < 8; u++) {
            int jj = j + u;
            si[u] = esrc[(jj < e) ? jj : (e - 1)];
        }
        ushort4 xv[8];
#pragma unroll
        for (int u = 0; u < 8; u++)
            xv[u] = *(const ushort4*)(H + (size_t)si[u] * 256 + lane * 4);
        float a[8];
#pragma unroll
        for (int u = 0; u < 8; u++)
            a[u] = (j + u < e) ? dinv[si[u]] * ddst : 0.f;
#pragma unroll
        for (int u = 0; u < 8; u++) {
            acc.x = fmaf(a[u], bf2f(xv[u].x), acc.x);
            acc.y = fmaf(a[u], bf2f(xv[u].y), acc.y);
            acc.z = fmaf(a[u], bf2f(xv[u].z), acc.z);
            acc.w = fmaf(a[u], bf2f(xv[u].w), acc.w);
        }
    }
    size_t o = (size_t)node * 256 + lane * 4;
    ushort4 hi;
    hi.x = f2bf(acc.x); hi.y = f2bf(acc.y);
    hi.z = f2bf(acc.z); hi.w = f2bf(acc.w);
    *(ushort4*)(Ah + o) = hi;
}

// ---------------- MFMA GEMM: C = relu(A @ W + b) ----------
// ASPLIT: A has hi+lo (3-term product) else hi only (2-term).
// Output always bf16.
template <int K, bool ASPLIT>
__launch_bounds__(256, 2)
__global__ void mfma_gemm_bias_relu(const unsigned short* __restrict__ Ah,
                                    const unsigned short* __restrict__ Al,
                                    const unsigned short* __restrict__ Bh,
                                    const unsigned short* __restrict__ Bl,
                                    const float* __restrict__ bias,
                                    unsigned short* __restrict__ Cout) {
    constexpr int NT = ASPLIT ? 4 : 3;
    __shared__ __align__(16) unsigned short lds[NT * 128 * 32];
    unsigned short* Ahs = lds;
    unsigned short* Als = lds + 4096;                    // only valid if ASPLIT
    unsigned short* Bhs = lds + (ASPLIT ? 8192 : 4096);
    unsigned short* Bls = lds + (ASPLIT ? 12288 : 8192);

    int tid = threadIdx.x;
    int bm = blockIdx.x * 128;
    int bn = blockIdx.y * 128;
    int wid = tid >> 6, lane = tid & 63;
    int wm = wid & 1, wn = wid >> 1;
    int lrow = lane & 15, quad = lane >> 4;

    f32x4 acc[4][4];
#pragma unroll
    for (int mi = 0; mi < 4; mi++)
#pragma unroll
        for (int ni = 0; ni < 4; ni++) acc[mi][ni] = (f32x4){0.f, 0.f, 0.f, 0.f};

    for (int k0 = 0; k0 < K; k0 += 32) {
#pragma unroll
        for (int i = 0; i < NT * 2; i++) {
            int c = tid + 256 * i;
            int tile = c >> 9;
            int w = c & 511;
            int row = w >> 2;
            int part = w & 3;
            const unsigned short* g;
            if (ASPLIT) {
                if (tile == 0)      g = Ah + (size_t)(bm + row) * K + k0 + part * 8;
                else if (tile == 1) g = Al + (size_t)(bm + row) * K + k0 + part * 8;
                else if (tile == 2) g = Bh + (size_t)(bn + row) * K + k0 + part * 8;
                else                g = Bl + (size_t)(bn + row) * K + k0 + part * 8;
            } else {
                if (tile == 0)      g = Ah + (size_t)(bm + row) * K + k0 + part * 8;
                else if (tile == 1) g = Bh + (size_t)(bn + row) * K + k0 + part * 8;
                else                g = Bl + (size_t)(bn + row) * K + k0 + part * 8;
            }
            ulonglong2 v = *(const ulonglong2*)g;
            *(ulonglong2*)&lds[(tile << 12) + row * 32 + part * 8] = v;
        }
        __syncthreads();

        bf16x8 ah[4], al[4], bh[4], bl[4];
#pragma unroll
        for (int mi = 0; mi < 4; mi++) {
            int r = wm * 64 + mi * 16 + lrow;
            ah[mi] = *(const bf16x8*)&Ahs[r * 32 + quad * 8];
            if (ASPLIT) al[mi] = *(const bf16x8*)&Als[r * 32 + quad * 8];
        }
#pragma unroll
        for (int ni = 0; ni < 4; ni++) {
            int r = wn * 64 + ni * 16 + lrow;
            bh[ni] = *(const bf16x8*)&Bhs[r * 32 + quad * 8];
            bl[ni] = *(const bf16x8*)&Bls[r * 32 + quad * 8];
        }
#pragma unroll
        for (int mi = 0; mi < 4; mi++)
#pragma unroll
            for (int ni = 0; ni < 4; ni++) {
                acc[mi][ni] = __builtin_amdgcn_mfma_f32_16x16x32_bf16(ah[mi], bh[ni], acc[mi][ni], 0, 0, 0);
                acc[mi][ni] = __builtin_amdgcn_mfma_f32_16x16x32_bf16(ah[mi], bl[ni], acc[mi][ni], 0, 0, 0);
                if (ASPLIT)
                    acc[mi][ni] = __builtin_amdgcn_mfma_f32_16x16x32_bf16(al[mi], bh[ni], acc[mi][ni], 0, 0, 0);
            }
        __syncthreads();
    }

    float bv[4];
#pragma unroll
    for (int ni = 0; ni < 4; ni++) bv[ni] = bias[bn + wn * 64 + ni * 16 + lrow];
#pragma unroll
    for (int mi = 0; mi < 4; mi++) {
        int row0 = bm + wm * 64 + mi * 16 + quad * 4;
#pragma unroll
        for (int ni = 0; ni < 4; ni++) {
            int col = bn + wn * 64 + ni * 16 + lrow;
#pragma unroll
            for (int r = 0; r < 4; r++) {
                int row = row0 + r;
                if (row < N_NODES) {
                    float v = fmaxf(acc[mi][ni][r] + bv[ni], 0.f);
                    Cout[(size_t)row * 256 + col] = f2bf(v);
                }
            }
        }
    }
}

// ---------------- fused mean-pool (batch sorted, h in bf16) + MLP head ----------
__global__ __launch_bounds__(256) void pool_mlp_kernel(const unsigned short* __restrict__ h,
                                                       const int* __restrict__ batch,
                                                       const float* __restrict__ Wf1,
                                                       const float* __restrict__ bf1,
                                                       const float* __restrict__ Wf2,
                                                       const float* __restrict__ bf2,
                                                       float* __restrict__ out) {
    int g = blockIdx.x;
    int t = threadIdx.x;  // 0..255
    __shared__ int bounds[2];
    if (t < 2) {
        int target = g + t;
        int lo = 0, hi = N_NODES;
        while (lo < hi) {
            int mid = (lo + hi) >> 1;
            if (batch[mid] < target) lo = mid + 1;
            else hi = mid;
        }
        bounds[t] = lo;
    }
    __syncthreads();
    int lo = bounds[0], hi = bounds[1];

    float acc = 0.f;
    for (int n = lo; n < hi; n++) acc += bf2f(h[(size_t)n * HID + t]);
    float inv = (hi > lo) ? 1.0f / (float)(hi - lo) : 0.f;
    __shared__ float p[256];
    p[t] = acc * inv;
    __syncthreads();

    float hv = 0.f;
    if (t < 128) {
        float a = bf1[t];
#pragma unroll 8
        for (int k = 0; k < 256; k++) a = fmaf(p[k], Wf1[k * 128 + t], a);
        hv = fmaxf(a, 0.f) * Wf2[t];
    }
#pragma unroll
    for (int off = 32; off > 0; off >>= 1) hv += __shfl_down(hv, off, 64);
    __shared__ float partial[4];
    if ((t & 63) == 0) partial[t >> 6] = hv;
    __syncthreads();
    if (t == 0) out[g] = partial[0] + partial[1] + bf2[0];
}

extern "C" void kernel_launch(void* const* d_in, const int* in_sizes, int n_in,
                              void* d_out, int out_size, void* d_ws, size_t ws_size,
                              hipStream_t stream) {
    const float* x   = (const float*)d_in[0];
    const int*   ei  = (const int*)d_in[1];
    const int*   bat = (const int*)d_in[2];
    const float* W1  = (const float*)d_in[3];
    const float* b1  = (const float*)d_in[4];
    const float* W2  = (const float*)d_in[5];
    const float* b2  = (const float*)d_in[6];
    const float* Wf1 = (const float*)d_in[7];
    const float* bf1 = (const float*)d_in[8];
    const float* Wf2 = (const float*)d_in[9];
    const float* bf2 = (const float*)d_in[10];
    float* out = (float*)d_out;

    char* ws = (char*)d_ws;
    // layout (peak end 0x9B20000 = 162.5 MB):
    //   0x0000000 deg        0x0080000 dinv      0x0100000 rowptr   0x0180000 fill
    //   0x01F0000 bsum
    //   0x0200000 esrc (6.4 MB)
    //   0x0820000 W1th  0x0830000 W1tl  0x0840000 W2th  0x0860000 W2tl
    //   0x0880000 A1h (25.6 MB) / later A2 (51.2 MB, single)
    //   0x20F0000 A1l (25.6 MB)  [A2 overlaps A1h+A1l: both dead by then]
    //   0x6A40000 xbf (25.6 MB) -> H1bf (51.2 MB) -> H2bf (51.2 MB) time-multiplexed
    int*   deg    = (int*)(ws);
    float* dinv   = (float*)(ws + 0x0080000);
    int*   rowptr = (int*)(ws + 0x0100000);
    int*   fill   = (int*)(ws + 0x0180000);
    int*   bsum   = (int*)(ws + 0x01F0000);
    int*   esrc   = (int*)(ws + 0x0200000);
    unsigned short* W1th = (unsigned short*)(ws + 0x0820000);
    unsigned short* W1tl = (unsigned short*)(ws + 0x0830000);
    unsigned short* W2th = (unsigned short*)(ws + 0x0840000);
    unsigned short* W2tl = (unsigned short*)(ws + 0x0860000);
    unsigned short* A1h  = (unsigned short*)(ws + 0x0880000);
    unsigned short* A1l  = (unsigned short*)(ws + 0x20F0000);
    unsigned short* A2   = (unsigned short*)(ws + 0x0880000);  // reuses A1h+A1l space
    unsigned short* xbf  = (unsigned short*)(ws + 0x6A40000);
    unsigned short* H1bf = (unsigned short*)(ws + 0x6A40000);  // overwrites dead xbf
    unsigned short* H2bf = (unsigned short*)(ws + 0x6A40000);  // overwrites dead H1bf
    (void)ws_size;

    hipMemsetAsync(deg, 0, (size_t)N_NODES * sizeof(int), stream);
    hipMemsetAsync(fill, 0, (size_t)N_NODES * sizeof(int), stream);

    // independent prep
    x2bf_kernel<<<(N_NODES * IN_DIM / 4) / 256, 256, 0, stream>>>(x, xbf);
    wsplit_all_kernel<<<((IN_DIM + HID) * 256) / 256, 256, 0, stream>>>(W1, W2, W1th, W1tl, W2th, W2tl);

    // CSR build
    count_deg_kernel<<<(N_EDGES + 255) / 256, 256, 0, stream>>>(ei, deg);
    blocksum_kernel<<<SCAN_BLOCKS, 1024, 0, stream>>>(deg, bsum, dinv);
    bscan_kernel<<<1, 128, 0, stream>>>(bsum);
    scanout_kernel<<<SCAN_BLOCKS, 1024, 0, stream>>>(deg, bsum, rowptr);
    fill_kernel<<<(N_EDGES + 255) / 256, 256, 0, stream>>>(ei, rowptr, fill, esrc);

    // layer 1: A1 = split(A~ x_bf16); H1bf = bf16(relu(A1 @ W1 + b1))  [3-term]
    agg128_kernel<<<N_NODES / 4, 256, 0, stream>>>(xbf, esrc, rowptr, dinv, A1h, A1l);
    {
        dim3 grid(M_PAD / 128, 2);
        mfma_gemm_bias_relu<IN_DIM, true><<<grid, 256, 0, stream>>>(A1h, A1l, W1th, W1tl, b1, H1bf);
    }

    // layer 2: A2 = bf16(A~ H1bf); H2bf = bf16(relu(A2 @ W2 + b2))  [2-term]
    agg256_kernel<<<N_NODES / 4, 256, 0, stream>>>(H1bf, esrc, rowptr, dinv, A2);
    {
        dim3 grid(M_PAD / 128, 2);
        mfma_gemm_bias_relu<HID, false><<<grid, 256, 0, stream>>>(A2, nullptr, W2th, W2tl, b2, H2bf);
    }

    // pooling + MLP head (bf16 h)
    pool_mlp_kernel<<<NUM_GRAPHS, 256, 0, stream>>>(H2bf, bat, Wf1, bf1, Wf2, bf2, out);
}

// Round 8
// 598.412 us; speedup vs baseline: 1.0805x; 1.0805x over previous
//
#include <hip/hip_runtime.h>
#include <hip/hip_bf16.h>

#define N_NODES 100000
#define N_EDGES 1600000
#define IN_DIM 128
#define HID 256
#define NUM_GRAPHS 2048
#define M_PAD 100096  // 782 * 128
#define SCAN_BLOCKS 98  // ceil(100000/1024)

typedef __bf16 bf16x8 __attribute__((ext_vector_type(8)));
typedef float f32x4 __attribute__((ext_vector_type(4)));

__device__ inline unsigned short f2bf(float x) {
    union { __hip_bfloat16 h; unsigned short u; } v;
    v.h = __float2bfloat16(x);
    return v.u;
}
__device__ inline float bf2f(unsigned short u) {
    return __uint_as_float(((unsigned int)u) << 16);
}

// ---------------- degree histogram over dst ----------------
__global__ void count_deg_kernel(const int* __restrict__ ei, int* __restrict__ deg) {
    int e = blockIdx.x * blockDim.x + threadIdx.x;
    if (e < N_EDGES) {
        atomicAdd(&deg[ei[N_EDGES + e]], 1);
    }
}

// ---------------- block sums (+ fused dinv) ----------------
__global__ __launch_bounds__(1024) void blocksum_kernel(const int* __restrict__ deg,
                                                        int* __restrict__ bsum,
                                                        float* __restrict__ dinv) {
    int i = blockIdx.x * 1024 + threadIdx.x;
    int v = (i < N_NODES) ? deg[i] : 0;
    if (i < N_NODES) dinv[i] = rsqrtf((float)(v + 1));  // self-loop adds 1
    __shared__ int s[1024];
    int t = threadIdx.x;
    s[t] = v;
    __syncthreads();
#pragma unroll
    for (int off = 512; off > 0; off >>= 1) {
        if (t < off) s[t] += s[t + off];
        __syncthreads();
    }
    if (t == 0) bsum[blockIdx.x] = s[0];
}

__global__ __launch_bounds__(128) void bscan_kernel(int* __restrict__ bsum) {
    __shared__ int s[128];
    int t = threadIdx.x;
    int v = (t < SCAN_BLOCKS) ? bsum[t] : 0;
    s[t] = v;
    __syncthreads();
#pragma unroll
    for (int off = 1; off < 128; off <<= 1) {
        int x = (t >= off) ? s[t - off] : 0;
        __syncthreads();
        s[t] += x;
        __syncthreads();
    }
    if (t < SCAN_BLOCKS) bsum[t] = (t > 0) ? s[t - 1] : 0;  // exclusive
}

__global__ __launch_bounds__(1024) void scanout_kernel(const int* __restrict__ deg,
                                                       const int* __restrict__ bsum,
                                                       int* __restrict__ rowptr) {
    int i = blockIdx.x * 1024 + threadIdx.x;
    int t = threadIdx.x;
    int v = (i < N_NODES) ? deg[i] : 0;
    __shared__ int s[1024];
    s[t] = v;
    __syncthreads();
#pragma unroll
    for (int off = 1; off < 1024; off <<= 1) {
        int x = (t >= off) ? s[t - off] : 0;
        __syncthreads();
        s[t] += x;
        __syncthreads();
    }
    int base = bsum[blockIdx.x];
    int excl = (t > 0) ? s[t - 1] : 0;
    if (i < N_NODES) rowptr[i] = base + excl;
    if (i == N_NODES - 1) rowptr[N_NODES] = base + s[t];
}

// ---------------- bucket fill: CSR src list sorted by dst ----------------
__global__ void fill_kernel(const int* __restrict__ ei, const int* __restrict__ rowptr,
                            int* __restrict__ fill, int* __restrict__ esrc) {
    int e = blockIdx.x * blockDim.x + threadIdx.x;
    if (e < N_EDGES) {
        int dst = ei[N_EDGES + e];
        int pos = rowptr[dst] + atomicAdd(&fill[dst], 1);
        esrc[pos] = ei[e];
    }
}

// ---------------- x -> bf16 ----------------
__global__ void x2bf_kernel(const float* __restrict__ x, unsigned short* __restrict__ xb) {
    size_t i = ((size_t)blockIdx.x * 256 + threadIdx.x) * 4;
    float4 v = *(const float4*)(x + i);
    ushort4 o;
    o.x = f2bf(v.x); o.y = f2bf(v.y); o.z = f2bf(v.z); o.w = f2bf(v.w);
    *(ushort4*)(xb + i) = o;
}

// ---------------- both weight transposes + bf16 splits in one launch ----------
__global__ void wsplit_all_kernel(const float* __restrict__ W1, const float* __restrict__ W2,
                                  unsigned short* __restrict__ W1th, unsigned short* __restrict__ W1tl,
                                  unsigned short* __restrict__ W2th, unsigned short* __restrict__ W2tl) {
    int idx = blockIdx.x * 256 + threadIdx.x;
    if (idx < IN_DIM * 256) {
        int k = idx >> 8, n = idx & 255;
        float w = W1[idx];
        unsigned short h = f2bf(w);
        unsigned short l = f2bf(w - bf2f(h));
        W1th[n * IN_DIM + k] = h;
        W1tl[n * IN_DIM + k] = l;
    } else {
        int i2 = idx - IN_DIM * 256;
        int k = i2 >> 8, n = i2 & 255;
        float w = W2[i2];
        unsigned short h = f2bf(w);
        unsigned short l = f2bf(w - bf2f(h));
        W2th[n * HID + k] = h;
        W2tl[n * HID + k] = l;
    }
}

// ---------------- gather agg 128-dim from bf16, writes bf16 hi/lo split ----------
// wave-uniform node/s/e/src via readfirstlane -> scalar addressing for gathers
__global__ __launch_bounds__(256) void agg128_kernel(const unsigned short* __restrict__ X,
                                                     const int* __restrict__ esrc,
                                                     const int* __restrict__ rowptr,
                                                     const float* __restrict__ dinv,
                                                     unsigned short* __restrict__ Ah,
                                                     unsigned short* __restrict__ Al) {
    int node = __builtin_amdgcn_readfirstlane(blockIdx.x * 4 + (threadIdx.x >> 6));
    int lane = threadIdx.x & 63;
    float ddst = dinv[node];
    int s = __builtin_amdgcn_readfirstlane(rowptr[node]);
    int e = __builtin_amdgcn_readfirstlane(rowptr[node + 1]);

    float w0 = ddst * ddst;
    ushort2 h0 = *((const ushort2*)(X + (size_t)node * 128) + lane);
    float2 acc = make_float2(w0 * bf2f(h0.x), w0 * bf2f(h0.y));

    int j = s;
    for (; j + 8 <= e; j += 8) {
        int si[8];
#pragma unroll
        for (int u = 0; u < 8; u++) si[u] = __builtin_amdgcn_readfirstlane(esrc[j + u]);
        ushort2 xv[8];
#pragma unroll
        for (int u = 0; u < 8; u++)
            xv[u] = *((const ushort2*)(X + (size_t)si[u] * 128) + lane);
        float a[8];
#pragma unroll
        for (int u = 0; u < 8; u++) a[u] = dinv[si[u]] * ddst;
#pragma unroll
        for (int u = 0; u < 8; u++) {
            acc.x = fmaf(a[u], bf2f(xv[u].x), acc.x);
            acc.y = fmaf(a[u], bf2f(xv[u].y), acc.y);
        }
    }
    for (; j + 4 <= e; j += 4) {
        int si[4];
#pragma unroll
        for (int u = 0; u < 4; u++) si[u] = __builtin_amdgcn_readfirstlane(esrc[j + u]);
        ushort2 xv[4];
#pragma unroll
        for (int u = 0; u < 4; u++)
            xv[u] = *((const ushort2*)(X + (size_t)si[u] * 128) + lane);
        float a[4];
#pragma unroll
        for (int u = 0; u < 4; u++) a[u] = dinv[si[u]] * ddst;
#pragma unroll
        for (int u = 0; u < 4; u++) {
            acc.x = fmaf(a[u], bf2f(xv[u].x), acc.x);
            acc.y = fmaf(a[u], bf2f(xv[u].y), acc.y);
        }
    }
    for (; j < e; j++) {
        int src = __builtin_amdgcn_readfirstlane(esrc[j]);
        float w = dinv[src] * ddst;
        ushort2 xv = *((const ushort2*)(X + (size_t)src * 128) + lane);
        acc.x = fmaf(w, bf2f(xv.x), acc.x);
        acc.y = fmaf(w, bf2f(xv.y), acc.y);
    }
    size_t o = (size_t)node * 128 + lane * 2;
    ushort2 hi, lo;
    hi.x = f2bf(acc.x); lo.x = f2bf(acc.x - bf2f(hi.x));
    hi.y = f2bf(acc.y); lo.y = f2bf(acc.y - bf2f(hi.y));
    *(ushort2*)(Ah + o) = hi;
    *(ushort2*)(Al + o) = lo;
}

// ---------------- gather agg 256-dim from bf16, writes bf16 (hi only) ----------
__global__ __launch_bounds__(256) void agg256_kernel(const unsigned short* __restrict__ H,
                                                     const int* __restrict__ esrc,
                                                     const int* __restrict__ rowptr,
                                                     const float* __restrict__ dinv,
                                                     unsigned short* __restrict__ Ah) {
    int node = __builtin_amdgcn_readfirstlane(blockIdx.x * 4 + (threadIdx.x >> 6));
    int lane = threadIdx.x & 63;
    float ddst = dinv[node];
    int s = __builtin_amdgcn_readfirstlane(rowptr[node]);
    int e = __builtin_amdgcn_readfirstlane(rowptr[node + 1]);

    float w0 = ddst * ddst;
    ushort4 h0 = *((const ushort4*)(H + (size_t)node * 256) + lane);
    float4 acc = make_float4(w0 * bf2f(h0.x), w0 * bf2f(h0.y),
                             w0 * bf2f(h0.z), w0 * bf2f(h0.w));

    int j = s;
    for (; j + 8 <= e; j += 8) {
        int si[8];
#pragma unroll
        for (int u = 0; u < 8; u++) si[u] = __builtin_amdgcn_readfirstlane(esrc[j + u]);
        ushort4 xv[8];
#pragma unroll
        for (int u = 0; u < 8; u++)
            xv[u] = *((const ushort4*)(H + (size_t)si[u] * 256) + lane);
        float a[8];
#pragma unroll
        for (int u = 0; u < 8; u++) a[u] = dinv[si[u]] * ddst;
#pragma unroll
        for (int u = 0; u < 8; u++) {
            acc.x = fmaf(a[u], bf2f(xv[u].x), acc.x);
            acc.y = fmaf(a[u], bf2f(xv[u].y), acc.y);
            acc.z = fmaf(a[u], bf2f(xv[u].z), acc.z);
            acc.w = fmaf(a[u], bf2f(xv[u].w), acc.w);
        }
    }
    for (; j + 4 <= e; j += 4) {
        int si[4];
#pragma unroll
        for (int u = 0; u < 4; u++) si[u] = __builtin_amdgcn_readfirstlane(esrc[j + u]);
        ushort4 xv[4];
#pragma unroll
        for (int u = 0; u < 4; u++)
            xv[u] = *((const ushort4*)(H + (size_t)si[u] * 256) + lane);
        float a[4];
#pragma unroll
        for (int u = 0; u < 4; u++) a[u] = dinv[si[u]] * ddst;
#pragma unroll
        for (int u = 0; u < 4; u++) {
            acc.x = fmaf(a[u], bf2f(xv[u].x), acc.x);
            acc.y = fmaf(a[u], bf2f(xv[u].y), acc.y);
            acc.z = fmaf(a[u], bf2f(xv[u].z), acc.z);
            acc.w = fmaf(a[u], bf2f(xv[u].w), acc.w);
        }
    }
    for (; j < e; j++) {
        int src = __builtin_amdgcn_readfirstlane(esrc[j]);
        float w = dinv[src] * ddst;
        ushort4 xv = *((const ushort4*)(H + (size_t)src * 256) + lane);
        acc.x = fmaf(w, bf2f(xv.x), acc.x);
        acc.y = fmaf(w, bf2f(xv.y), acc.y);
        acc.z = fmaf(w, bf2f(xv.z), acc.z);
        acc.w = fmaf(w, bf2f(xv.w), acc.w);
    }
    size_t o = (size_t)node * 256 + lane * 4;
    ushort4 hi;
    hi.x = f2bf(acc.x); hi.y = f2bf(acc.y);
    hi.z = f2bf(acc.z); hi.w = f2bf(acc.w);
    *(ushort4*)(Ah + o) = hi;
}

// ---------------- MFMA GEMM: C = relu(A @ W + b) ----------
// ASPLIT: A has hi+lo (3-term product) else hi only (2-term). Output bf16.
template <int K, bool ASPLIT>
__launch_bounds__(256, 2)
__global__ void mfma_gemm_bias_relu(const unsigned short* __restrict__ Ah,
                                    const unsigned short* __restrict__ Al,
                                    const unsigned short* __restrict__ Bh,
                                    const unsigned short* __restrict__ Bl,
                                    const float* __restrict__ bias,
                                    unsigned short* __restrict__ Cout) {
    constexpr int NT = ASPLIT ? 4 : 3;
    __shared__ __align__(16) unsigned short lds[NT * 128 * 32];
    unsigned short* Ahs = lds;
    unsigned short* Als = lds + 4096;                    // only valid if ASPLIT
    unsigned short* Bhs = lds + (ASPLIT ? 8192 : 4096);
    unsigned short* Bls = lds + (ASPLIT ? 12288 : 8192);

    int tid = threadIdx.x;
    int bm = blockIdx.x * 128;
    int bn = blockIdx.y * 128;
    int wid = tid >> 6, lane = tid & 63;
    int wm = wid & 1, wn = wid >> 1;
    int lrow = lane & 15, quad = lane >> 4;

    f32x4 acc[4][4];
#pragma unroll
    for (int mi = 0; mi < 4; mi++)
#pragma unroll
        for (int ni = 0; ni < 4; ni++) acc[mi][ni] = (f32x4){0.f, 0.f, 0.f, 0.f};

    for (int k0 = 0; k0 < K; k0 += 32) {
#pragma unroll
        for (int i = 0; i < NT * 2; i++) {
            int c = tid + 256 * i;
            int tile = c >> 9;
            int w = c & 511;
            int row = w >> 2;
            int part = w & 3;
            const unsigned short* g;
            if (ASPLIT) {
                if (tile == 0)      g = Ah + (size_t)(bm + row) * K + k0 + part * 8;
                else if (tile == 1) g = Al + (size_t)(bm + row) * K + k0 + part * 8;
                else if (tile == 2) g = Bh + (size_t)(bn + row) * K + k0 + part * 8;
                else                g = Bl + (size_t)(bn + row) * K + k0 + part * 8;
            } else {
                if (tile == 0)      g = Ah + (size_t)(bm + row) * K + k0 + part * 8;
                else if (tile == 1) g = Bh + (size_t)(bn + row) * K + k0 + part * 8;
                else                g = Bl + (size_t)(bn + row) * K + k0 + part * 8;
            }
            ulonglong2 v = *(const ulonglong2*)g;
            *(ulonglong2*)&lds[(tile << 12) + row * 32 + part * 8] = v;
        }
        __syncthreads();

        bf16x8 ah[4], al[4], bh[4], bl[4];
#pragma unroll
        for (int mi = 0; mi < 4; mi++) {
            int r = wm * 64 + mi * 16 + lrow;
            ah[mi] = *(const bf16x8*)&Ahs[r * 32 + quad * 8];
            if (ASPLIT) al[mi] = *(const bf16x8*)&Als[r * 32 + quad * 8];
        }
#pragma unroll
        for (int ni = 0; ni < 4; ni++) {
            int r = wn * 64 + ni * 16 + lrow;
            bh[ni] = *(const bf16x8*)&Bhs[r * 32 + quad * 8];
            bl[ni] = *(const bf16x8*)&Bls[r * 32 + quad * 8];
        }
#pragma unroll
        for (int mi = 0; mi < 4; mi++)
#pragma unroll
            for (int ni = 0; ni < 4; ni++) {
                acc[mi][ni] = __builtin_amdgcn_mfma_f32_16x16x32_bf16(ah[mi], bh[ni], acc[mi][ni], 0, 0, 0);
                acc[mi][ni] = __builtin_amdgcn_mfma_f32_16x16x32_bf16(ah[mi], bl[ni], acc[mi][ni], 0, 0, 0);
                if (ASPLIT)
                    acc[mi][ni] = __builtin_amdgcn_mfma_f32_16x16x32_bf16(al[mi], bh[ni], acc[mi][ni], 0, 0, 0);
            }
        __syncthreads();
    }

    float bv[4];
#pragma unroll
    for (int ni = 0; ni < 4; ni++) bv[ni] = bias[bn + wn * 64 + ni * 16 + lrow];
#pragma unroll
    for (int mi = 0; mi < 4; mi++) {
        int row0 = bm + wm * 64 + mi * 16 + quad * 4;
#pragma unroll
        for (int ni = 0; ni < 4; ni++) {
            int col = bn + wn * 64 + ni * 16 + lrow;
#pragma unroll
            for (int r = 0; r < 4; r++) {
                int row = row0 + r;
                if (row < N_NODES) {
                    float v = fmaxf(acc[mi][ni][r] + bv[ni], 0.f);
                    Cout[(size_t)row * 256 + col] = f2bf(v);
                }
            }
        }
    }
}

// ---------------- fused mean-pool (batch sorted, h in bf16) + MLP head ----------
__global__ __launch_bounds__(256) void pool_mlp_kernel(const unsigned short* __restrict__ h,
                                                       const int* __restrict__ batch,
                                                       const float* __restrict__ Wf1,
                                                       const float* __restrict__ bf1,
                                                       const float* __restrict__ Wf2,
                                                       const float* __restrict__ bf2,
                                                       float* __restrict__ out) {
    int g = blockIdx.x;
    int t = threadIdx.x;  // 0..255
    __shared__ int bounds[2];
    if (t < 2) {
        int target = g + t;
        int lo = 0, hi = N_NODES;
        while (lo < hi) {
            int mid = (lo + hi) >> 1;
            if (batch[mid] < target) lo = mid + 1;
            else hi = mid;
        }
        bounds[t] = lo;
    }
    __syncthreads();
    int lo = bounds[0], hi = bounds[1];

    float acc = 0.f;
    for (int n = lo; n < hi; n++) acc += bf2f(h[(size_t)n * HID + t]);
    float inv = (hi > lo) ? 1.0f / (float)(hi - lo) : 0.f;
    __shared__ float p[256];
    p[t] = acc * inv;
    __syncthreads();

    float hv = 0.f;
    if (t < 128) {
        float a = bf1[t];
#pragma unroll 8
        for (int k = 0; k < 256; k++) a = fmaf(p[k], Wf1[k * 128 + t], a);
        hv = fmaxf(a, 0.f) * Wf2[t];
    }
#pragma unroll
    for (int off = 32; off > 0; off >>= 1) hv += __shfl_down(hv, off, 64);
    __shared__ float partial[4];
    if ((t & 63) == 0) partial[t >> 6] = hv;
    __syncthreads();
    if (t == 0) out[g] = partial[0] + partial[1] + bf2[0];
}

extern "C" void kernel_launch(void* const* d_in, const int* in_sizes, int n_in,
                              void* d_out, int out_size, void* d_ws, size_t ws_size,
                              hipStream_t stream) {
    const float* x   = (const float*)d_in[0];
    const int*   ei  = (const int*)d_in[1];
    const int*   bat = (const int*)d_in[2];
    const float* W1  = (const float*)d_in[3];
    const float* b1  = (const float*)d_in[4];
    const float* W2  = (const float*)d_in[5];
    const float* b2  = (const float*)d_in[6];
    const float* Wf1 = (const float*)d_in[7];
    const float* bf1 = (const float*)d_in[8];
    const float* Wf2 = (const float*)d_in[9];
    const float* bf2 = (const float*)d_in[10];
    float* out = (float*)d_out;

    char* ws = (char*)d_ws;
    // layout (peak end 0x9B20000 = 162.5 MB):
    //   0x0000000 deg        0x0080000 dinv      0x0100000 rowptr   0x0180000 fill
    //   0x01F0000 bsum
    //   0x0200000 esrc (6.4 MB)
    //   0x0820000 W1th  0x0830000 W1tl  0x0840000 W2th  0x0860000 W2tl
    //   0x0880000 A1h (25.6 MB) / later A2 (51.2 MB, single)
    //   0x20F0000 A1l (25.6 MB)  [A2 overlaps A1h+A1l: both dead by then]
    //   0x6A40000 xbf (25.6 MB) -> H1bf (51.2 MB) -> H2bf (51.2 MB) time-multiplexed
    int*   deg    = (int*)(ws);
    float* dinv   = (float*)(ws + 0x0080000);
    int*   rowptr = (int*)(ws + 0x0100000);
    int*   fill   = (int*)(ws + 0x0180000);
    int*   bsum   = (int*)(ws + 0x01F0000);
    int*   esrc   = (int*)(ws + 0x0200000);
    unsigned short* W1th = (unsigned short*)(ws + 0x0820000);
    unsigned short* W1tl = (unsigned short*)(ws + 0x0830000);
    unsigned short* W2th = (unsigned short*)(ws + 0x0840000);
    unsigned short* W2tl = (unsigned short*)(ws + 0x0860000);
    unsigned short* A1h  = (unsigned short*)(ws + 0x0880000);
    unsigned short* A1l  = (unsigned short*)(ws + 0x20F0000);
    unsigned short* A2   = (unsigned short*)(ws + 0x0880000);  // reuses A1h+A1l space
    unsigned short* xbf  = (unsigned short*)(ws + 0x6A40000);
    unsigned short* H1bf = (unsigned short*)(ws + 0x6A40000);  // overwrites dead xbf
    unsigned short* H2bf = (unsigned short*)(ws + 0x6A40000);  // overwrites dead H1bf
    (void)ws_size;

    hipMemsetAsync(deg, 0, (size_t)N_NODES * sizeof(int), stream);
    hipMemsetAsync(fill, 0, (size_t)N_NODES * sizeof(int), stream);

    // independent prep
    x2bf_kernel<<<(N_NODES * IN_DIM / 4) / 256, 256, 0, stream>>>(x, xbf);
    wsplit_all_kernel<<<((IN_DIM + HID) * 256) / 256, 256, 0, stream>>>(W1, W2, W1th, W1tl, W2th, W2tl);

    // CSR build
    count_deg_kernel<<<(N_EDGES + 255) / 256, 256, 0, stream>>>(ei, deg);
    blocksum_kernel<<<SCAN_BLOCKS, 1024, 0, stream>>>(deg, bsum, dinv);
    bscan_kernel<<<1, 128, 0, stream>>>(bsum);
    scanout_kernel<<<SCAN_BLOCKS, 1024, 0, stream>>>(deg, bsum, rowptr);
    fill_kernel<<<(N_EDGES + 255) / 256, 256, 0, stream>>>(ei, rowptr, fill, esrc);

    // layer 1: A1 = split(A~ x_bf16); H1bf = bf16(relu(A1 @ W1 + b1))  [3-term]
    agg128_kernel<<<N_NODES / 4, 256, 0, stream>>>(xbf, esrc, rowptr, dinv, A1h, A1l);
    {
        dim3 grid(M_PAD / 128, 2);
        mfma_gemm_bias_relu<IN_DIM, true><<<grid, 256, 0, stream>>>(A1h, A1l, W1th, W1tl, b1, H1bf);
    }

    // layer 2: A2 = bf16(A~ H1bf); H2bf = bf16(relu(A2 @ W2 + b2))  [2-term]
    agg256_kernel<<<N_NODES / 4, 256, 0, stream>>>(H1bf, esrc, rowptr, dinv, A2);
    {
        dim3 grid(M_PAD / 128, 2);
        mfma_gemm_bias_relu<HID, false><<<grid, 256, 0, stream>>>(A2, nullptr, W2th, W2tl, b2, H2bf);
    }

    // pooling + MLP head (bf16 h)
    pool_mlp_kernel<<<NUM_GRAPHS, 256, 0, stream>>>(H2bf, bat, Wf1, bf1, Wf2, bf2, out);
}